// Round 15
// baseline (122.124 us; speedup 1.0000x reference)
//
#include <hip/hip_runtime.h>
#include <hip/hip_bf16.h>
#include <math.h>

typedef _Float16 f16_t;
typedef _Float16 f16x4 __attribute__((ext_vector_type(4)));
typedef _Float16 f16x8 __attribute__((ext_vector_type(8)));
typedef float f32x4 __attribute__((ext_vector_type(4)));

#define BATCH 131072
#define MTILE 64               // rows per block (4 waves, 16 rows/wave)
#define NBLK (BATCH / MTILE)

// fragment-layout weight offsets in d_ws (elements, f16)
#define W1F 0
#define W2F 4096
#define W3F 20480
#define W4F 36864

// ---------------------------------------------------------------------------
// Kernel A: fp32 weights -> fp16 MFMA B-fragment layout.
// B-frag (mfma_f32_16x16x32_f16): lane holds 8 contiguous-k f16:
//   col = tile*16 + (lane&15), k = kstep*32 + (lane>>4)*8 + j
// W4 laid out as 8 chunks x 92 cols padded to 96 (6 tiles).
// ---------------------------------------------------------------------------
__global__ __launch_bounds__(256) void convert_weights_kernel(
    const float* __restrict__ W1, const float* __restrict__ W2,
    const float* __restrict__ W3, const float* __restrict__ W4,
    f16_t* __restrict__ wf) {
  int tid = blockIdx.x * 256 + threadIdx.x;
  if (tid >= 16896) return;
  int lane = tid & 63;
  int l16 = lane & 15, lhi = lane >> 4;
  const float* W; int ncols, col, k0; bool zero = false;
  if (tid < 512) {
    int n = tid >> 6;
    W = W1; ncols = 128; col = n * 16 + l16; k0 = lhi * 8;
  } else if (tid < 2560) {
    int g = tid - 512; int n = g >> 8, s = (g >> 6) & 3;
    W = W2; ncols = 128; col = n * 16 + l16; k0 = s * 32 + lhi * 8;
  } else if (tid < 4608) {
    int g = tid - 2560; int n = g >> 8, s = (g >> 6) & 3;
    W = W3; ncols = 128; col = n * 16 + l16; k0 = s * 32 + lhi * 8;
  } else {
    int g = tid - 4608; int t = g >> 8, s = (g >> 6) & 3;
    int c = t / 6, n = t - c * 6;
    int colc = n * 16 + l16;
    W = W4; ncols = 736; col = c * 92 + colc; k0 = s * 32 + lhi * 8;
    zero = (colc >= 92);
  }
  f16x8 v;
#pragma unroll
  for (int j = 0; j < 8; ++j)
    v[j] = zero ? (f16_t)0.f : (f16_t)W[(k0 + j) * ncols + col];
  *(f16x8*)(wf + (size_t)tid * 8) = v;
}

__device__ __forceinline__ float elu(float v) {
  return v > 0.f ? v : (__expf(v) - 1.f);
}

// ---------------------------------------------------------------------------
// spline for one (row, dim) task; P = 24-f16 param slot (16B-aligned).
// Lean form + deferred softplus (R12/R13-validated).
// ---------------------------------------------------------------------------
__device__ __forceinline__ void rqs_task(const f16_t* P, float xv,
                                         float& yout, float& ldout) {
  f16x8 pw = *(const f16x8*)P;
  f16x8 ph = *(const f16x8*)(P + 8);
  f16x8 pd = *(const f16x8*)(P + 16);   // [7] is pad, unused

  float ew[8], sw = 0.f;
#pragma unroll
  for (int i = 0; i < 8; ++i) { ew[i] = __expf((float)pw[i]); sw += ew[i]; }
  float invw = 0.992f * __builtin_amdgcn_rcpf(sw);
  float cw[9]; cw[0] = -3.f;
  float accw = 0.f;
#pragma unroll
  for (int i = 0; i < 8; ++i) {
    accw += 0.001f + ew[i] * invw;
    cw[i + 1] = -3.f + 6.f * accw;
  }
  cw[8] = 3.f;
  float wd[8];
#pragma unroll
  for (int i = 0; i < 8; ++i) wd[i] = cw[i + 1] - cw[i];

  float eh[8], sh = 0.f;
#pragma unroll
  for (int i = 0; i < 8; ++i) { eh[i] = __expf((float)ph[i]); sh += eh[i]; }
  float invh = 0.992f * __builtin_amdgcn_rcpf(sh);
  float ch[9]; ch[0] = -3.f;
  float acch = 0.f;
#pragma unroll
  for (int i = 0; i < 8; ++i) {
    acch += 0.001f + eh[i] * invh;
    ch[i + 1] = -3.f + 6.f * acch;
  }
  ch[8] = 3.f;
  float ht[8];
#pragma unroll
  for (int i = 0; i < 8; ++i) ht[i] = ch[i + 1] - ch[i];

  float xc = fminf(fmaxf(xv, -3.f), 3.f);
  int bin = 0;
#pragma unroll
  for (int i = 1; i < 8; ++i) bin += (xc >= cw[i]) ? 1 : 0;

  float in_cw = cw[0], in_w = wd[0], in_ch = ch[0], in_h = ht[0];
  float sd  = (float)pd[0];
  float sd1 = (float)pd[0];
#pragma unroll
  for (int i = 1; i < 8; ++i) {
    bool g = (bin >= i);
    in_cw = g ? cw[i] : in_cw;  in_w = g ? wd[i] : in_w;
    in_ch = g ? ch[i] : in_ch;  in_h = g ? ht[i] : in_h;
    sd    = g ? (float)pd[i - 1] : sd;
  }
#pragma unroll
  for (int i = 1; i < 7; ++i)
    sd1 = (bin >= i) ? (float)pd[i] : sd1;

  float spd  = fmaxf(sd,  0.f) + __logf(1.f + __expf(-fabsf(sd)));
  float spd1 = fmaxf(sd1, 0.f) + __logf(1.f + __expf(-fabsf(sd1)));
  float in_d  = (bin == 0) ? 1.f : 0.001f + spd;
  float in_d1 = (bin == 7) ? 1.f : 0.001f + spd1;

  float rw = __builtin_amdgcn_rcpf(in_w);
  float dlt = in_h * rw;
  float th = (xc - in_cw) * rw;
  float om = 1.f - th;
  float t1 = th * om;
  float num = in_h * (dlt * th * th + in_d * t1);
  float den = dlt + (in_d + in_d1 - 2.f * dlt) * t1;
  float rden = __builtin_amdgcn_rcpf(den);
  float yo = in_ch + num * rden;
  float dn = dlt * dlt * (in_d1 * th * th + 2.f * dlt * t1 + in_d * om * om);
  float ldv = __logf(dn * rden * rden);
  bool inside = (xv >= -3.f) && (xv <= 3.f);
  yout = inside ? yo : xv;
  ldout = inside ? ldv : 0.f;
}

// ---------------------------------------------------------------------------
// middle MLP layer: in-place on the wave's 16-row strip of hH.
// ---------------------------------------------------------------------------
__device__ __forceinline__ void mid_layer_ip(f16_t* hH,
                                             const f16_t* __restrict__ wseg,
                                             const float* __restrict__ bg,
                                             int wv, int l16, int lhi, int lane) {
  f16x8 a[4];
#pragma unroll
  for (int s = 0; s < 4; ++s)
    a[s] = *(const f16x8*)&hH[(wv * 16 + l16) * 136 + s * 32 + lhi * 8];
#pragma unroll
  for (int n = 0; n < 8; ++n) {
    f32x4 acc = {0.f, 0.f, 0.f, 0.f};
#pragma unroll
    for (int s = 0; s < 4; ++s) {
      f16x8 b = *(const f16x8*)(wseg + (size_t)((n * 4 + s) * 64 + lane) * 8);
      acc = __builtin_amdgcn_mfma_f32_16x16x32_f16(a[s], b, acc, 0, 0, 0);
    }
    float bias = bg[n * 16 + l16];
#pragma unroll
    for (int r = 0; r < 4; ++r)
      hH[(wv * 16 + lhi * 4 + r) * 136 + n * 16 + l16] =
          (f16_t)elu(acc[r] + bias);
  }
}

// ---------------------------------------------------------------------------
// Kernel B (R13 + double-buffered prm, ONE barrier per chunk):
// 64 rows/block, 4 waves. Buffer B aliases the dead hH region (a4 fragments
// are register-resident, guarded by a barrier). Hazard: S(c) reads buf[c&1];
// next writer G(c+2) is separated from it by barrier B(c+1). LDS unchanged:
// 17408 (hH) + 12288 (prm) + 8448 (x2s) = 38144 B -> 4 blocks/CU.
// ---------------------------------------------------------------------------
__global__ __launch_bounds__(256, 4) void nsf_fused_kernel(
    const float* __restrict__ x,
    const float* __restrict__ b1g, const float* __restrict__ b2g,
    const float* __restrict__ b3g, const float* __restrict__ b4g,
    const f16_t* __restrict__ wf,
    float* __restrict__ out) {
  __shared__ f16_t hH[MTILE * 136];       // hidden state; later aliased as bufB
  __shared__ f16_t prm[MTILE * 4 * 24];   // spline params bufA
  __shared__ float x2s[MTILE * 33];       // x2 tile, fp32

  const int tid = threadIdx.x;
  const int lane = tid & 63;
  const int wv = tid >> 6;
  const int l16 = lane & 15, lhi = lane >> 4;
  const int row0 = blockIdx.x * MTILE;

  // ---- stage x: x1 -> out + hH (f16), x2 -> x2s (f32) ----
  {
    const float4* x4 = (const float4*)(x + (size_t)row0 * 64);
    float4* o4 = (float4*)(out + (size_t)row0 * 64);
#pragma unroll
    for (int it = 0; it < 4; ++it) {
      int idx = tid + it * 256;          // 0..1023 = 64 rows x 16 float4
      int row = idx >> 4, q = idx & 15;
      float4 v = x4[row * 16 + q];
      if (q < 8) {                       // x1 cols 0..31
        o4[row * 16 + q] = v;
        f16x4 p = {(f16_t)v.x, (f16_t)v.y, (f16_t)v.z, (f16_t)v.w};
        *(f16x4*)&hH[row * 136 + q * 4] = p;
      } else {                           // x2 cols 32..63
        int cb = row * 33 + (q - 8) * 4;
        x2s[cb + 0] = v.x; x2s[cb + 1] = v.y;
        x2s[cb + 2] = v.z; x2s[cb + 3] = v.w;
      }
    }
  }
  __syncthreads();

  // ---- layer 1: (64x32)@(32x128), K=32, in-place ----
  {
    f16x8 a = *(const f16x8*)&hH[(wv * 16 + l16) * 136 + lhi * 8];
#pragma unroll
    for (int n = 0; n < 8; ++n) {
      f16x8 b = *(const f16x8*)(wf + W1F + (size_t)(n * 64 + lane) * 8);
      f32x4 acc = {0.f, 0.f, 0.f, 0.f};
      acc = __builtin_amdgcn_mfma_f32_16x16x32_f16(a, b, acc, 0, 0, 0);
      float bias = b1g[n * 16 + l16];
#pragma unroll
      for (int r = 0; r < 4; ++r)
        hH[(wv * 16 + lhi * 4 + r) * 136 + n * 16 + l16] =
            (f16_t)elu(acc[r] + bias);
    }
  }
  __syncthreads();

  mid_layer_ip(hH, wf + W2F, b2g, wv, l16, lhi, lane);   // layer 2
  __syncthreads();
  mid_layer_ip(hH, wf + W3F, b3g, wv, l16, lhi, lane);   // layer 3
  __syncthreads();

  // ---- layer 4 + spline: double-buffered prm, 1 barrier per chunk ----
  {
    f16x8 a4[4];
#pragma unroll
    for (int s = 0; s < 4; ++s)
      a4[s] = *(const f16x8*)&hH[(wv * 16 + l16) * 136 + s * 32 + lhi * 8];
    __syncthreads();   // all a4 in registers -> hH region reusable as bufB

    f16_t* bufA = prm;
    f16_t* bufB = hH;            // 12288 B needed, 17408 B available
    const int srow = tid >> 2;   // spline row 0..63
    const int sjj = tid & 3;     // chunk-local spline dim
    float ldp = 0.f;

    for (int c = 0; c < 8; ++c) {
      f16_t* buf = (c & 1) ? bufB : bufA;

      // GEMM4 chunk: 92 real cols (4 dims x 23) padded to 96 (6 tiles)
#pragma unroll
      for (int n = 0; n < 6; ++n) {
        f32x4 acc = {0.f, 0.f, 0.f, 0.f};
#pragma unroll
        for (int s = 0; s < 4; ++s) {
          f16x8 b = *(const f16x8*)(wf + W4F +
                      (size_t)(((c * 6 + n) * 4 + s) * 64 + lane) * 8);
          acc = __builtin_amdgcn_mfma_f32_16x16x32_f16(a4[s], b, acc, 0, 0, 0);
        }
        int colc = n * 16 + l16;
        if (colc < 92) {
          int dm = (colc * 90) >> 11;          // colc / 23 for colc < 92
          int j = colc - dm * 23;
          float bias = b4g[c * 92 + colc];
#pragma unroll
          for (int r = 0; r < 4; ++r)
            buf[((wv * 16 + lhi * 4 + r) * 4 + dm) * 24 + j] =
                (f16_t)(acc[r] + bias);
        }
      }
      __syncthreads();   // the ONLY barrier in the chunk loop

      // ---- spline: one (row, dim) task per thread; then straight into
      //      next chunk's GEMM loads (no trailing barrier) ----
      {
        int jg = c * 4 + sjj;
        float xv = x2s[srow * 33 + jg];
        float y0, l0;
        rqs_task(buf + (srow * 4 + sjj) * 24, xv, y0, l0);
        out[(size_t)(row0 + srow) * 64 + 32 + jg] = y0;
        ldp += l0;
      }
    }

    // ---- log_det: quad reduce over sjj ----
    ldp += __shfl_xor(ldp, 1, 64);
    ldp += __shfl_xor(ldp, 2, 64);
    if ((tid & 3) == 0)
      out[(size_t)BATCH * 64 + row0 + srow] = ldp;
  }
}

// ---------------------------------------------------------------------------
extern "C" void kernel_launch(void* const* d_in, const int* in_sizes, int n_in,
                              void* d_out, int out_size, void* d_ws, size_t ws_size,
                              hipStream_t stream) {
  const float* x  = (const float*)d_in[0];
  const float* W1 = (const float*)d_in[1];
  const float* b1 = (const float*)d_in[2];
  const float* W2 = (const float*)d_in[3];
  const float* b2 = (const float*)d_in[4];
  const float* W3 = (const float*)d_in[5];
  const float* b3 = (const float*)d_in[6];
  const float* W4 = (const float*)d_in[7];
  const float* b4 = (const float*)d_in[8];
  f16_t* wf = (f16_t*)d_ws;
  float* out = (float*)d_out;

  hipLaunchKernelGGL(convert_weights_kernel, dim3(66), dim3(256), 0, stream,
                     W1, W2, W3, W4, wf);
  hipLaunchKernelGGL(nsf_fused_kernel, dim3(NBLK), dim3(256), 0, stream,
                     x, b1, b2, b3, b4, wf, out);
}

// Round 16
// 117.355 us; speedup vs baseline: 1.0406x; 1.0406x over previous
//
#include <hip/hip_runtime.h>
#include <hip/hip_bf16.h>
#include <math.h>

typedef _Float16 f16_t;
typedef _Float16 f16x4 __attribute__((ext_vector_type(4)));
typedef _Float16 f16x8 __attribute__((ext_vector_type(8)));
typedef float f32x4 __attribute__((ext_vector_type(4)));

#define BATCH 131072
#define MTILE 64               // rows per block (4 waves, 16 rows/wave)
#define NBLK (BATCH / MTILE)

// fragment-layout weight offsets in d_ws (elements, f16)
#define W1F 0
#define W2F 4096
#define W3F 20480
#define W4F 36864

// ---------------------------------------------------------------------------
// Kernel A: fp32 weights -> fp16 MFMA B-fragment layout.
// B-frag (mfma_f32_16x16x32_f16): lane holds 8 contiguous-k f16:
//   col = tile*16 + (lane&15), k = kstep*32 + (lane>>4)*8 + j
// W4 laid out as 8 chunks x 92 cols padded to 96 (6 tiles).
// ---------------------------------------------------------------------------
__global__ __launch_bounds__(256) void convert_weights_kernel(
    const float* __restrict__ W1, const float* __restrict__ W2,
    const float* __restrict__ W3, const float* __restrict__ W4,
    f16_t* __restrict__ wf) {
  int tid = blockIdx.x * 256 + threadIdx.x;
  if (tid >= 16896) return;
  int lane = tid & 63;
  int l16 = lane & 15, lhi = lane >> 4;
  const float* W; int ncols, col, k0; bool zero = false;
  if (tid < 512) {
    int n = tid >> 6;
    W = W1; ncols = 128; col = n * 16 + l16; k0 = lhi * 8;
  } else if (tid < 2560) {
    int g = tid - 512; int n = g >> 8, s = (g >> 6) & 3;
    W = W2; ncols = 128; col = n * 16 + l16; k0 = s * 32 + lhi * 8;
  } else if (tid < 4608) {
    int g = tid - 2560; int n = g >> 8, s = (g >> 6) & 3;
    W = W3; ncols = 128; col = n * 16 + l16; k0 = s * 32 + lhi * 8;
  } else {
    int g = tid - 4608; int t = g >> 8, s = (g >> 6) & 3;
    int c = t / 6, n = t - c * 6;
    int colc = n * 16 + l16;
    W = W4; ncols = 736; col = c * 92 + colc; k0 = s * 32 + lhi * 8;
    zero = (colc >= 92);
  }
  f16x8 v;
#pragma unroll
  for (int j = 0; j < 8; ++j)
    v[j] = zero ? (f16_t)0.f : (f16_t)W[(k0 + j) * ncols + col];
  *(f16x8*)(wf + (size_t)tid * 8) = v;
}

__device__ __forceinline__ float elu(float v) {
  return v > 0.f ? v : (__expf(v) - 1.f);
}

// ---------------------------------------------------------------------------
// spline for one (row, dim) task; P = 24-f16 param slot (16B-aligned).
// Lean form + deferred softplus (R12/R13-validated).
// ---------------------------------------------------------------------------
__device__ __forceinline__ void rqs_task(const f16_t* P, float xv,
                                         float& yout, float& ldout) {
  f16x8 pw = *(const f16x8*)P;
  f16x8 ph = *(const f16x8*)(P + 8);
  f16x8 pd = *(const f16x8*)(P + 16);   // [7] is pad, unused

  float ew[8], sw = 0.f;
#pragma unroll
  for (int i = 0; i < 8; ++i) { ew[i] = __expf((float)pw[i]); sw += ew[i]; }
  float invw = 0.992f * __builtin_amdgcn_rcpf(sw);
  float cw[9]; cw[0] = -3.f;
  float accw = 0.f;
#pragma unroll
  for (int i = 0; i < 8; ++i) {
    accw += 0.001f + ew[i] * invw;
    cw[i + 1] = -3.f + 6.f * accw;
  }
  cw[8] = 3.f;
  float wd[8];
#pragma unroll
  for (int i = 0; i < 8; ++i) wd[i] = cw[i + 1] - cw[i];

  float eh[8], sh = 0.f;
#pragma unroll
  for (int i = 0; i < 8; ++i) { eh[i] = __expf((float)ph[i]); sh += eh[i]; }
  float invh = 0.992f * __builtin_amdgcn_rcpf(sh);
  float ch[9]; ch[0] = -3.f;
  float acch = 0.f;
#pragma unroll
  for (int i = 0; i < 8; ++i) {
    acch += 0.001f + eh[i] * invh;
    ch[i + 1] = -3.f + 6.f * acch;
  }
  ch[8] = 3.f;
  float ht[8];
#pragma unroll
  for (int i = 0; i < 8; ++i) ht[i] = ch[i + 1] - ch[i];

  float xc = fminf(fmaxf(xv, -3.f), 3.f);
  int bin = 0;
#pragma unroll
  for (int i = 1; i < 8; ++i) bin += (xc >= cw[i]) ? 1 : 0;

  float in_cw = cw[0], in_w = wd[0], in_ch = ch[0], in_h = ht[0];
  float sd  = (float)pd[0];
  float sd1 = (float)pd[0];
#pragma unroll
  for (int i = 1; i < 8; ++i) {
    bool g = (bin >= i);
    in_cw = g ? cw[i] : in_cw;  in_w = g ? wd[i] : in_w;
    in_ch = g ? ch[i] : in_ch;  in_h = g ? ht[i] : in_h;
    sd    = g ? (float)pd[i - 1] : sd;
  }
#pragma unroll
  for (int i = 1; i < 7; ++i)
    sd1 = (bin >= i) ? (float)pd[i] : sd1;

  float spd  = fmaxf(sd,  0.f) + __logf(1.f + __expf(-fabsf(sd)));
  float spd1 = fmaxf(sd1, 0.f) + __logf(1.f + __expf(-fabsf(sd1)));
  float in_d  = (bin == 0) ? 1.f : 0.001f + spd;
  float in_d1 = (bin == 7) ? 1.f : 0.001f + spd1;

  float rw = __builtin_amdgcn_rcpf(in_w);
  float dlt = in_h * rw;
  float th = (xc - in_cw) * rw;
  float om = 1.f - th;
  float t1 = th * om;
  float num = in_h * (dlt * th * th + in_d * t1);
  float den = dlt + (in_d + in_d1 - 2.f * dlt) * t1;
  float rden = __builtin_amdgcn_rcpf(den);
  float yo = in_ch + num * rden;
  float dn = dlt * dlt * (in_d1 * th * th + 2.f * dlt * t1 + in_d * om * om);
  float ldv = __logf(dn * rden * rden);
  bool inside = (xv >= -3.f) && (xv <= 3.f);
  yout = inside ? yo : xv;
  ldout = inside ? ldv : 0.f;
}

// ---------------------------------------------------------------------------
// middle MLP layer: in-place on the wave's 16-row strip of hH.
// ---------------------------------------------------------------------------
__device__ __forceinline__ void mid_layer_ip(f16_t* hH,
                                             const f16_t* __restrict__ wseg,
                                             const float* __restrict__ bg,
                                             int wv, int l16, int lhi, int lane) {
  f16x8 a[4];
#pragma unroll
  for (int s = 0; s < 4; ++s)
    a[s] = *(const f16x8*)&hH[(wv * 16 + l16) * 136 + s * 32 + lhi * 8];
#pragma unroll
  for (int n = 0; n < 8; ++n) {
    f32x4 acc = {0.f, 0.f, 0.f, 0.f};
#pragma unroll
    for (int s = 0; s < 4; ++s) {
      f16x8 b = *(const f16x8*)(wseg + (size_t)((n * 4 + s) * 64 + lane) * 8);
      acc = __builtin_amdgcn_mfma_f32_16x16x32_f16(a[s], b, acc, 0, 0, 0);
    }
    float bias = bg[n * 16 + l16];
#pragma unroll
    for (int r = 0; r < 4; ++r)
      hH[(wv * 16 + lhi * 4 + r) * 136 + n * 16 + l16] =
          (f16_t)elu(acc[r] + bias);
  }
}

// ---------------------------------------------------------------------------
// Kernel B (R13 + static-double-buffer paired chunks):
// 64 rows/block, 4 waves. Even chunks -> prm, odd chunks -> hH (dead after
// a4 hoist; STATIC symbol, no dynamic pointer -> addresses stay constant-
// folded and the c-loop fully unrolls). Each barrier-free region pairs a
// spline (VALU) with the next chunk's GEMM (global loads + MFMA, different
// LDS array) so the scheduler overlaps them. Barriers 17 -> 9.
// LDS: 17408 (hH) + 12288 (prm) + 8448 (x2s) = 38144 B -> 4 blocks/CU.
// ---------------------------------------------------------------------------
__global__ __launch_bounds__(256, 4) void nsf_fused_kernel(
    const float* __restrict__ x,
    const float* __restrict__ b1g, const float* __restrict__ b2g,
    const float* __restrict__ b3g, const float* __restrict__ b4g,
    const f16_t* __restrict__ wf,
    float* __restrict__ out) {
  __shared__ f16_t hH[MTILE * 136];       // hidden state; later spline buf B
  __shared__ f16_t prm[MTILE * 4 * 24];   // spline buf A
  __shared__ float x2s[MTILE * 33];       // x2 tile, fp32

  const int tid = threadIdx.x;
  const int lane = tid & 63;
  const int wv = tid >> 6;
  const int l16 = lane & 15, lhi = lane >> 4;
  const int row0 = blockIdx.x * MTILE;

  // ---- stage x: x1 -> out + hH (f16), x2 -> x2s (f32) ----
  {
    const float4* x4 = (const float4*)(x + (size_t)row0 * 64);
    float4* o4 = (float4*)(out + (size_t)row0 * 64);
#pragma unroll
    for (int it = 0; it < 4; ++it) {
      int idx = tid + it * 256;          // 0..1023 = 64 rows x 16 float4
      int row = idx >> 4, q = idx & 15;
      float4 v = x4[row * 16 + q];
      if (q < 8) {                       // x1 cols 0..31
        o4[row * 16 + q] = v;
        f16x4 p = {(f16_t)v.x, (f16_t)v.y, (f16_t)v.z, (f16_t)v.w};
        *(f16x4*)&hH[row * 136 + q * 4] = p;
      } else {                           // x2 cols 32..63
        int cb = row * 33 + (q - 8) * 4;
        x2s[cb + 0] = v.x; x2s[cb + 1] = v.y;
        x2s[cb + 2] = v.z; x2s[cb + 3] = v.w;
      }
    }
  }
  __syncthreads();

  // ---- layer 1: (64x32)@(32x128), K=32, in-place ----
  {
    f16x8 a = *(const f16x8*)&hH[(wv * 16 + l16) * 136 + lhi * 8];
#pragma unroll
    for (int n = 0; n < 8; ++n) {
      f16x8 b = *(const f16x8*)(wf + W1F + (size_t)(n * 64 + lane) * 8);
      f32x4 acc = {0.f, 0.f, 0.f, 0.f};
      acc = __builtin_amdgcn_mfma_f32_16x16x32_f16(a, b, acc, 0, 0, 0);
      float bias = b1g[n * 16 + l16];
#pragma unroll
      for (int r = 0; r < 4; ++r)
        hH[(wv * 16 + lhi * 4 + r) * 136 + n * 16 + l16] =
            (f16_t)elu(acc[r] + bias);
    }
  }
  __syncthreads();

  mid_layer_ip(hH, wf + W2F, b2g, wv, l16, lhi, lane);   // layer 2
  __syncthreads();
  mid_layer_ip(hH, wf + W3F, b3g, wv, l16, lhi, lane);   // layer 3
  __syncthreads();

  // ---- layer 4 + spline: 4 unrolled chunk-pairs, static double buffer ----
  {
    f16x8 a4[4];
#pragma unroll
    for (int s = 0; s < 4; ++s)
      a4[s] = *(const f16x8*)&hH[(wv * 16 + l16) * 136 + s * 32 + lhi * 8];
    __syncthreads();   // a4 in registers -> hH reusable as spline buf B

    const int srow = tid >> 2;   // spline row 0..63
    const int sjj = tid & 3;     // chunk-local spline dim
    float ldp = 0.f;

#pragma unroll
    for (int cp = 0; cp < 4; ++cp) {
      const int cA = 2 * cp, cB = 2 * cp + 1;

      // ---- G(cA) -> prm ----
#pragma unroll
      for (int n = 0; n < 6; ++n) {
        f32x4 acc = {0.f, 0.f, 0.f, 0.f};
#pragma unroll
        for (int s = 0; s < 4; ++s) {
          f16x8 b = *(const f16x8*)(wf + W4F +
                      (size_t)(((cA * 6 + n) * 4 + s) * 64 + lane) * 8);
          acc = __builtin_amdgcn_mfma_f32_16x16x32_f16(a4[s], b, acc, 0, 0, 0);
        }
        int colc = n * 16 + l16;
        if (colc < 92) {
          int dm = (colc * 90) >> 11;          // colc / 23 for colc < 92
          int j = colc - dm * 23;
          float bias = b4g[cA * 92 + colc];
#pragma unroll
          for (int r = 0; r < 4; ++r)
            prm[((wv * 16 + lhi * 4 + r) * 4 + dm) * 24 + j] =
                (f16_t)(acc[r] + bias);
        }
      }
      __syncthreads();

      // ---- region: S(cA) reads prm  ||  G(cB) writes hH (no barrier) ----
      {
        int jg = cA * 4 + sjj;
        float xv = x2s[srow * 33 + jg];
        float y0, l0;
        rqs_task(prm + (srow * 4 + sjj) * 24, xv, y0, l0);
        out[(size_t)(row0 + srow) * 64 + 32 + jg] = y0;
        ldp += l0;
      }
#pragma unroll
      for (int n = 0; n < 6; ++n) {
        f32x4 acc = {0.f, 0.f, 0.f, 0.f};
#pragma unroll
        for (int s = 0; s < 4; ++s) {
          f16x8 b = *(const f16x8*)(wf + W4F +
                      (size_t)(((cB * 6 + n) * 4 + s) * 64 + lane) * 8);
          acc = __builtin_amdgcn_mfma_f32_16x16x32_f16(a4[s], b, acc, 0, 0, 0);
        }
        int colc = n * 16 + l16;
        if (colc < 92) {
          int dm = (colc * 90) >> 11;
          int j = colc - dm * 23;
          float bias = b4g[cB * 92 + colc];
#pragma unroll
          for (int r = 0; r < 4; ++r)
            hH[((wv * 16 + lhi * 4 + r) * 4 + dm) * 24 + j] =
                (f16_t)(acc[r] + bias);
        }
      }
      __syncthreads();

      // ---- region: S(cB) reads hH  ||  next pair's G(cA') (no barrier) ----
      {
        int jg = cB * 4 + sjj;
        float xv = x2s[srow * 33 + jg];
        float y0, l0;
        rqs_task(hH + (srow * 4 + sjj) * 24, xv, y0, l0);
        out[(size_t)(row0 + srow) * 64 + 32 + jg] = y0;
        ldp += l0;
      }
    }

    // ---- log_det: quad reduce over sjj ----
    ldp += __shfl_xor(ldp, 1, 64);
    ldp += __shfl_xor(ldp, 2, 64);
    if ((tid & 3) == 0)
      out[(size_t)BATCH * 64 + row0 + srow] = ldp;
  }
}

// ---------------------------------------------------------------------------
extern "C" void kernel_launch(void* const* d_in, const int* in_sizes, int n_in,
                              void* d_out, int out_size, void* d_ws, size_t ws_size,
                              hipStream_t stream) {
  const float* x  = (const float*)d_in[0];
  const float* W1 = (const float*)d_in[1];
  const float* b1 = (const float*)d_in[2];
  const float* W2 = (const float*)d_in[3];
  const float* b2 = (const float*)d_in[4];
  const float* W3 = (const float*)d_in[5];
  const float* b3 = (const float*)d_in[6];
  const float* W4 = (const float*)d_in[7];
  const float* b4 = (const float*)d_in[8];
  f16_t* wf = (f16_t*)d_ws;
  float* out = (float*)d_out;

  hipLaunchKernelGGL(convert_weights_kernel, dim3(66), dim3(256), 0, stream,
                     W1, W2, W3, W4, wf);
  hipLaunchKernelGGL(nsf_fused_kernel, dim3(NBLK), dim3(256), 0, stream,
                     x, b1, b2, b3, b4, wf, out);
}

// Round 17
// 111.427 us; speedup vs baseline: 1.0960x; 1.0532x over previous
//
#include <hip/hip_runtime.h>
#include <hip/hip_bf16.h>
#include <math.h>

typedef _Float16 f16_t;
typedef _Float16 f16x4 __attribute__((ext_vector_type(4)));
typedef _Float16 f16x8 __attribute__((ext_vector_type(8)));
typedef float f32x4 __attribute__((ext_vector_type(4)));

#define BATCH 131072
#define MTILE 64               // rows per block (4 waves, 16 rows/wave)
#define NBLK (BATCH / MTILE)
#define LOG2E 1.4426950408889634f

// fragment-layout weight offsets in d_ws (elements, f16)
#define W1F 0
#define W2F 4096
#define W3F 20480
#define W4F 36864
#define B4S_OFF 67584          // float index into d_ws (byte 270336), 736 floats

// ---------------------------------------------------------------------------
// Kernel A: fp32 weights -> fp16 MFMA B-fragment layout.
//   col = tile*16 + (lane&15), k = kstep*32 + (lane>>4)*8 + j
// W4 laid out as 8 chunks x 92 cols padded to 96 (6 tiles).
// W4's softmax columns (col%23 < 16) are PRE-SCALED by log2(e) so the
// spline can use raw v_exp_f32 (2^x); b4 likewise -> b4s (fp32, in d_ws).
// ---------------------------------------------------------------------------
__global__ __launch_bounds__(256) void convert_weights_kernel(
    const float* __restrict__ W1, const float* __restrict__ W2,
    const float* __restrict__ W3, const float* __restrict__ W4,
    const float* __restrict__ b4, f16_t* __restrict__ wf,
    float* __restrict__ b4s) {
  int tid = blockIdx.x * 256 + threadIdx.x;
  if (tid >= 16896) {                    // tail: scale b4 -> b4s
    int i = tid - 16896;
    if (i < 736) {
      float s = ((i % 23) < 16) ? LOG2E : 1.f;
      b4s[i] = b4[i] * s;
    }
    return;
  }
  int lane = tid & 63;
  int l16 = lane & 15, lhi = lane >> 4;
  const float* W; int ncols, col, k0; bool zero = false; float scale = 1.f;
  if (tid < 512) {
    int n = tid >> 6;
    W = W1; ncols = 128; col = n * 16 + l16; k0 = lhi * 8;
  } else if (tid < 2560) {
    int g = tid - 512; int n = g >> 8, s = (g >> 6) & 3;
    W = W2; ncols = 128; col = n * 16 + l16; k0 = s * 32 + lhi * 8;
  } else if (tid < 4608) {
    int g = tid - 2560; int n = g >> 8, s = (g >> 6) & 3;
    W = W3; ncols = 128; col = n * 16 + l16; k0 = s * 32 + lhi * 8;
  } else {
    int g = tid - 4608; int t = g >> 8, s = (g >> 6) & 3;
    int c = t / 6, n = t - c * 6;
    int colc = n * 16 + l16;
    W = W4; ncols = 736; col = c * 92 + colc; k0 = s * 32 + lhi * 8;
    zero = (colc >= 92);
    if (!zero) scale = ((col % 23) < 16) ? LOG2E : 1.f;
  }
  f16x8 v;
#pragma unroll
  for (int j = 0; j < 8; ++j)
    v[j] = zero ? (f16_t)0.f : (f16_t)(W[(k0 + j) * ncols + col] * scale);
  *(f16x8*)(wf + (size_t)tid * 8) = v;
}

__device__ __forceinline__ float elu(float v) {
  return v > 0.f ? v : (__expf(v) - 1.f);
}

// ---------------------------------------------------------------------------
// spline for one (row, dim) task; P = 24-f16 param slot (16B-aligned).
// pw/ph are in log2 domain (pre-scaled weights) -> exp2f = bare v_exp_f32.
// Deferred softplus (R12/R13); select-then-fma for in_w/in_h.
// ---------------------------------------------------------------------------
__device__ __forceinline__ void rqs_task(const f16_t* P, float xv,
                                         float& yout, float& ldout) {
  f16x8 pw = *(const f16x8*)P;
  f16x8 ph = *(const f16x8*)(P + 8);
  f16x8 pd = *(const f16x8*)(P + 16);   // [7] is pad, unused

  float ew[8], sw = 0.f;
#pragma unroll
  for (int i = 0; i < 8; ++i) { ew[i] = exp2f((float)pw[i]); sw += ew[i]; }
  float invw = 0.992f * __builtin_amdgcn_rcpf(sw);
  float cw[8]; cw[0] = -3.f;
  float accw = 0.f;
#pragma unroll
  for (int i = 0; i < 7; ++i) {
    accw += 0.001f + ew[i] * invw;
    cw[i + 1] = -3.f + 6.f * accw;
  }

  float eh[8], sh = 0.f;
#pragma unroll
  for (int i = 0; i < 8; ++i) { eh[i] = exp2f((float)ph[i]); sh += eh[i]; }
  float invh = 0.992f * __builtin_amdgcn_rcpf(sh);
  float ch[8]; ch[0] = -3.f;
  float acch = 0.f;
#pragma unroll
  for (int i = 0; i < 7; ++i) {
    acch += 0.001f + eh[i] * invh;
    ch[i + 1] = -3.f + 6.f * acch;
  }

  float xc = fminf(fmaxf(xv, -3.f), 3.f);
  int bin = 0;
#pragma unroll
  for (int i = 1; i < 8; ++i) bin += (xc >= cw[i]) ? 1 : 0;

  // gather via unrolled select chains (static indices -> registers)
  float in_cw = cw[0], in_ch = ch[0];
  float ewsel = ew[0], ehsel = eh[0];
  float sd  = (float)pd[0];
  float sd1 = (float)pd[0];
#pragma unroll
  for (int i = 1; i < 8; ++i) {
    bool g = (bin >= i);
    in_cw = g ? cw[i] : in_cw;  in_ch = g ? ch[i] : in_ch;
    ewsel = g ? ew[i] : ewsel;  ehsel = g ? eh[i] : ehsel;
    sd    = g ? (float)pd[i - 1] : sd;
  }
#pragma unroll
  for (int i = 1; i < 7; ++i)
    sd1 = (bin >= i) ? (float)pd[i] : sd1;

  float in_w = fmaf(ewsel * invw, 6.f, 0.006f);   // width of selected bin
  float in_h = fmaf(ehsel * invh, 6.f, 0.006f);   // height of selected bin

  float spd  = fmaxf(sd,  0.f) + __logf(1.f + __expf(-fabsf(sd)));
  float spd1 = fmaxf(sd1, 0.f) + __logf(1.f + __expf(-fabsf(sd1)));
  float in_d  = (bin == 0) ? 1.f : 0.001f + spd;
  float in_d1 = (bin == 7) ? 1.f : 0.001f + spd1;

  float rw = __builtin_amdgcn_rcpf(in_w);
  float dlt = in_h * rw;
  float th = (xc - in_cw) * rw;
  float om = 1.f - th;
  float t1 = th * om;
  float num = in_h * (dlt * th * th + in_d * t1);
  float den = dlt + (in_d + in_d1 - 2.f * dlt) * t1;
  float rden = __builtin_amdgcn_rcpf(den);
  float yo = in_ch + num * rden;
  float dn = dlt * dlt * (in_d1 * th * th + 2.f * dlt * t1 + in_d * om * om);
  float ldv = __logf(dn * rden * rden);
  bool inside = (xv >= -3.f) && (xv <= 3.f);
  yout = inside ? yo : xv;
  ldout = inside ? ldv : 0.f;
}

// ---------------------------------------------------------------------------
// middle MLP layer: in-place on the wave's 16-row strip of hH.
// ---------------------------------------------------------------------------
__device__ __forceinline__ void mid_layer_ip(f16_t* hH,
                                             const f16_t* __restrict__ wseg,
                                             const float* __restrict__ bg,
                                             int wv, int l16, int lhi, int lane) {
  f16x8 a[4];
#pragma unroll
  for (int s = 0; s < 4; ++s)
    a[s] = *(const f16x8*)&hH[(wv * 16 + l16) * 136 + s * 32 + lhi * 8];
#pragma unroll
  for (int n = 0; n < 8; ++n) {
    f32x4 acc = {0.f, 0.f, 0.f, 0.f};
#pragma unroll
    for (int s = 0; s < 4; ++s) {
      f16x8 b = *(const f16x8*)(wseg + (size_t)((n * 4 + s) * 64 + lane) * 8);
      acc = __builtin_amdgcn_mfma_f32_16x16x32_f16(a[s], b, acc, 0, 0, 0);
    }
    float bias = bg[n * 16 + l16];
#pragma unroll
    for (int r = 0; r < 4; ++r)
      hH[(wv * 16 + lhi * 4 + r) * 136 + n * 16 + l16] =
          (f16_t)elu(acc[r] + bias);
  }
}

// GEMM4 chunk, COMPUTE ONLY (global loads + MFMA; no LDS ops -> vmcnt domain)
__device__ __forceinline__ void gemm4_chunk(const f16_t* __restrict__ wf4,
                                            const f16x8 a4[4], int lane,
                                            f32x4 acc[6]) {
#pragma unroll
  for (int n = 0; n < 6; ++n) {
    acc[n] = {0.f, 0.f, 0.f, 0.f};
#pragma unroll
    for (int s = 0; s < 4; ++s) {
      f16x8 b = *(const f16x8*)(wf4 + (size_t)((n * 4 + s) * 64 + lane) * 8);
      acc[n] = __builtin_amdgcn_mfma_f32_16x16x32_f16(a4[s], b, acc[n], 0, 0, 0);
    }
  }
}

// GEMM4 chunk, STORE ONLY (the only ds_writes; placed after barrier)
__device__ __forceinline__ void store_chunk(f16_t* prm, const f32x4 acc[6],
                                            const float* __restrict__ b4s,
                                            int c, int wv, int l16, int lhi) {
#pragma unroll
  for (int n = 0; n < 6; ++n) {
    int colc = n * 16 + l16;
    if (colc < 92) {
      int dm = (colc * 90) >> 11;          // colc / 23 for colc < 92
      int j = colc - dm * 23;
      float bias = b4s[c * 92 + colc];
#pragma unroll
      for (int r = 0; r < 4; ++r)
        prm[((wv * 16 + lhi * 4 + r) * 4 + dm) * 24 + j] =
            (f16_t)(acc[n][r] + bias);
    }
  }
}

// ---------------------------------------------------------------------------
// Kernel B (R13 structure + register-pipelined W4 GEMM):
// chunk c+1's loads+MFMAs (vmcnt only) run BEFORE spline(c) (lgkmcnt only)
// -> true overlap with no counter crosstalk; prm stores happen after the
// barrier (single buffer, R13 hazard structure preserved, 2 barriers/chunk).
// LDS: 17408 (hH) + 12288 (prm) + 8448 (x2s) = 38144 B -> 4 blocks/CU.
// ---------------------------------------------------------------------------
__global__ __launch_bounds__(256, 4) void nsf_fused_kernel(
    const float* __restrict__ x,
    const float* __restrict__ b1g, const float* __restrict__ b2g,
    const float* __restrict__ b3g, const float* __restrict__ b4s,
    const f16_t* __restrict__ wf,
    float* __restrict__ out) {
  __shared__ f16_t hH[MTILE * 136];       // hidden state, in-place across layers
  __shared__ f16_t prm[MTILE * 4 * 24];   // spline params chunk, f16 24-slots
  __shared__ float x2s[MTILE * 33];       // x2 tile, fp32

  const int tid = threadIdx.x;
  const int lane = tid & 63;
  const int wv = tid >> 6;
  const int l16 = lane & 15, lhi = lane >> 4;
  const int row0 = blockIdx.x * MTILE;

  // ---- stage x: x1 -> out + hH (f16), x2 -> x2s (f32) ----
  {
    const float4* x4 = (const float4*)(x + (size_t)row0 * 64);
    float4* o4 = (float4*)(out + (size_t)row0 * 64);
#pragma unroll
    for (int it = 0; it < 4; ++it) {
      int idx = tid + it * 256;          // 0..1023 = 64 rows x 16 float4
      int row = idx >> 4, q = idx & 15;
      float4 v = x4[row * 16 + q];
      if (q < 8) {                       // x1 cols 0..31
        o4[row * 16 + q] = v;
        f16x4 p = {(f16_t)v.x, (f16_t)v.y, (f16_t)v.z, (f16_t)v.w};
        *(f16x4*)&hH[row * 136 + q * 4] = p;
      } else {                           // x2 cols 32..63
        int cb = row * 33 + (q - 8) * 4;
        x2s[cb + 0] = v.x; x2s[cb + 1] = v.y;
        x2s[cb + 2] = v.z; x2s[cb + 3] = v.w;
      }
    }
  }
  __syncthreads();

  // ---- layer 1: (64x32)@(32x128), K=32, in-place ----
  {
    f16x8 a = *(const f16x8*)&hH[(wv * 16 + l16) * 136 + lhi * 8];
#pragma unroll
    for (int n = 0; n < 8; ++n) {
      f16x8 b = *(const f16x8*)(wf + W1F + (size_t)(n * 64 + lane) * 8);
      f32x4 acc = {0.f, 0.f, 0.f, 0.f};
      acc = __builtin_amdgcn_mfma_f32_16x16x32_f16(a, b, acc, 0, 0, 0);
      float bias = b1g[n * 16 + l16];
#pragma unroll
      for (int r = 0; r < 4; ++r)
        hH[(wv * 16 + lhi * 4 + r) * 136 + n * 16 + l16] =
            (f16_t)elu(acc[r] + bias);
    }
  }
  __syncthreads();

  mid_layer_ip(hH, wf + W2F, b2g, wv, l16, lhi, lane);   // layer 2
  __syncthreads();
  mid_layer_ip(hH, wf + W3F, b3g, wv, l16, lhi, lane);   // layer 3
  __syncthreads();

  // ---- layer 4 + spline, register-pipelined across chunks ----
  {
    f16x8 a4[4];
#pragma unroll
    for (int s = 0; s < 4; ++s)
      a4[s] = *(const f16x8*)&hH[(wv * 16 + l16) * 136 + s * 32 + lhi * 8];

    const int srow = tid >> 2;   // spline row 0..63
    const int sjj = tid & 3;     // chunk-local spline dim
    float ldp = 0.f;
    f32x4 accn[6];               // register-resident next-chunk GEMM result

    // prologue: chunk 0
    gemm4_chunk(wf + W4F, a4, lane, accn);
    store_chunk(prm, accn, b4s, 0, wv, l16, lhi);
    __syncthreads();

#pragma unroll
    for (int c = 0; c < 8; ++c) {
      // compute chunk c+1 into registers (loads+MFMA only) while the
      // spline below chews on chunk c
      if (c < 7)
        gemm4_chunk(wf + W4F + (size_t)(c + 1) * 6 * 4 * 64 * 8, a4, lane, accn);

      // ---- spline: one (row, dim) task per thread ----
      {
        int jg = c * 4 + sjj;
        float xv = x2s[srow * 33 + jg];
        float y0, l0;
        rqs_task(prm + (srow * 4 + sjj) * 24, xv, y0, l0);
        out[(size_t)(row0 + srow) * 64 + 32 + jg] = y0;
        ldp += l0;
      }
      __syncthreads();               // all reads of chunk c done

      if (c < 7) {
        store_chunk(prm, accn, b4s, c + 1, wv, l16, lhi);
        __syncthreads();             // chunk c+1 visible for next S
      }
    }

    // ---- log_det: quad reduce over sjj ----
    ldp += __shfl_xor(ldp, 1, 64);
    ldp += __shfl_xor(ldp, 2, 64);
    if ((tid & 3) == 0)
      out[(size_t)BATCH * 64 + row0 + srow] = ldp;
  }
}

// ---------------------------------------------------------------------------
extern "C" void kernel_launch(void* const* d_in, const int* in_sizes, int n_in,
                              void* d_out, int out_size, void* d_ws, size_t ws_size,
                              hipStream_t stream) {
  const float* x  = (const float*)d_in[0];
  const float* W1 = (const float*)d_in[1];
  const float* b1 = (const float*)d_in[2];
  const float* W2 = (const float*)d_in[3];
  const float* b2 = (const float*)d_in[4];
  const float* W3 = (const float*)d_in[5];
  const float* b3 = (const float*)d_in[6];
  const float* W4 = (const float*)d_in[7];
  const float* b4 = (const float*)d_in[8];
  f16_t* wf = (f16_t*)d_ws;
  float* b4s = (float*)d_ws + B4S_OFF;
  float* out = (float*)d_out;

  hipLaunchKernelGGL(convert_weights_kernel, dim3(69), dim3(256), 0, stream,
                     W1, W2, W3, W4, b4, wf, b4s);
  hipLaunchKernelGGL(nsf_fused_kernel, dim3(NBLK), dim3(256), 0, stream,
                     x, b1, b2, b3, b4s, wf, out);
}

// Round 18
// 97.997 us; speedup vs baseline: 1.2462x; 1.1370x over previous
//
#include <hip/hip_runtime.h>
#include <hip/hip_bf16.h>
#include <math.h>

typedef _Float16 f16_t;
typedef _Float16 f16x4 __attribute__((ext_vector_type(4)));
typedef _Float16 f16x8 __attribute__((ext_vector_type(8)));
typedef float f32x4 __attribute__((ext_vector_type(4)));

#define BATCH 131072
#define MTILE 64               // rows per block (4 waves, 16 rows/wave)
#define NBLK (BATCH / MTILE)
#define LOG2E 1.4426950408889634f

// fragment-layout weight offsets in d_ws (elements, f16)
#define W1F 0
#define W2F 4096
#define W3F 20480
#define W4F 36864
#define B4S_OFF 67584          // float index into d_ws, 736 floats

// ---------------------------------------------------------------------------
// Kernel A: fp32 weights -> fp16 MFMA B-fragment layout.
//   col = tile*16 + (lane&15), k = kstep*32 + (lane>>4)*8 + j
// W4 laid out as 8 chunks x 92 cols padded to 96 (6 tiles).
// W4's softmax columns (col%23 < 16) are PRE-SCALED by log2(e) so the
// spline can use exp2f (bare v_exp_f32); b4 likewise -> b4s (fp32).
// ---------------------------------------------------------------------------
__global__ __launch_bounds__(256) void convert_weights_kernel(
    const float* __restrict__ W1, const float* __restrict__ W2,
    const float* __restrict__ W3, const float* __restrict__ W4,
    const float* __restrict__ b4, f16_t* __restrict__ wf,
    float* __restrict__ b4s) {
  int tid = blockIdx.x * 256 + threadIdx.x;
  if (tid >= 16896) {                    // tail: scale b4 -> b4s
    int i = tid - 16896;
    if (i < 736) {
      float s = ((i % 23) < 16) ? LOG2E : 1.f;
      b4s[i] = b4[i] * s;
    }
    return;
  }
  int lane = tid & 63;
  int l16 = lane & 15, lhi = lane >> 4;
  const float* W; int ncols, col, k0; bool zero = false; float scale = 1.f;
  if (tid < 512) {
    int n = tid >> 6;
    W = W1; ncols = 128; col = n * 16 + l16; k0 = lhi * 8;
  } else if (tid < 2560) {
    int g = tid - 512; int n = g >> 8, s = (g >> 6) & 3;
    W = W2; ncols = 128; col = n * 16 + l16; k0 = s * 32 + lhi * 8;
  } else if (tid < 4608) {
    int g = tid - 2560; int n = g >> 8, s = (g >> 6) & 3;
    W = W3; ncols = 128; col = n * 16 + l16; k0 = s * 32 + lhi * 8;
  } else {
    int g = tid - 4608; int t = g >> 8, s = (g >> 6) & 3;
    int c = t / 6, n = t - c * 6;
    int colc = n * 16 + l16;
    W = W4; ncols = 736; col = c * 92 + colc; k0 = s * 32 + lhi * 8;
    zero = (colc >= 92);
    if (!zero) scale = ((col % 23) < 16) ? LOG2E : 1.f;
  }
  f16x8 v;
#pragma unroll
  for (int j = 0; j < 8; ++j)
    v[j] = zero ? (f16_t)0.f : (f16_t)(W[(k0 + j) * ncols + col] * scale);
  *(f16x8*)(wf + (size_t)tid * 8) = v;
}

__device__ __forceinline__ float elu(float v) {
  return v > 0.f ? v : (__expf(v) - 1.f);
}

// ---------------------------------------------------------------------------
// spline for one (row, dim) task; P = 24-f16 param slot (16B-aligned).
// pw/ph in log2 domain (pre-scaled weights) -> exp2f = bare v_exp_f32.
// Deferred softplus (R12/R13); select-then-fma for in_w/in_h (R17-validated).
// ---------------------------------------------------------------------------
__device__ __forceinline__ void rqs_task(const f16_t* P, float xv,
                                         float& yout, float& ldout) {
  f16x8 pw = *(const f16x8*)P;
  f16x8 ph = *(const f16x8*)(P + 8);
  f16x8 pd = *(const f16x8*)(P + 16);   // [7] is pad, unused

  float ew[8], sw = 0.f;
#pragma unroll
  for (int i = 0; i < 8; ++i) { ew[i] = exp2f((float)pw[i]); sw += ew[i]; }
  float invw = 0.992f * __builtin_amdgcn_rcpf(sw);
  float cw[8]; cw[0] = -3.f;
  float accw = 0.f;
#pragma unroll
  for (int i = 0; i < 7; ++i) {
    accw += 0.001f + ew[i] * invw;
    cw[i + 1] = -3.f + 6.f * accw;
  }

  float eh[8], sh = 0.f;
#pragma unroll
  for (int i = 0; i < 8; ++i) { eh[i] = exp2f((float)ph[i]); sh += eh[i]; }
  float invh = 0.992f * __builtin_amdgcn_rcpf(sh);
  float ch[8]; ch[0] = -3.f;
  float acch = 0.f;
#pragma unroll
  for (int i = 0; i < 7; ++i) {
    acch += 0.001f + eh[i] * invh;
    ch[i + 1] = -3.f + 6.f * acch;
  }

  float xc = fminf(fmaxf(xv, -3.f), 3.f);
  int bin = 0;
#pragma unroll
  for (int i = 1; i < 8; ++i) bin += (xc >= cw[i]) ? 1 : 0;

  // gather via unrolled select chains (static indices -> registers)
  float in_cw = cw[0], in_ch = ch[0];
  float ewsel = ew[0], ehsel = eh[0];
  float sd  = (float)pd[0];
  float sd1 = (float)pd[0];
#pragma unroll
  for (int i = 1; i < 8; ++i) {
    bool g = (bin >= i);
    in_cw = g ? cw[i] : in_cw;  in_ch = g ? ch[i] : in_ch;
    ewsel = g ? ew[i] : ewsel;  ehsel = g ? eh[i] : ehsel;
    sd    = g ? (float)pd[i - 1] : sd;
  }
#pragma unroll
  for (int i = 1; i < 7; ++i)
    sd1 = (bin >= i) ? (float)pd[i] : sd1;

  float in_w = fmaf(ewsel * invw, 6.f, 0.006f);   // width of selected bin
  float in_h = fmaf(ehsel * invh, 6.f, 0.006f);   // height of selected bin

  float spd  = fmaxf(sd,  0.f) + __logf(1.f + __expf(-fabsf(sd)));
  float spd1 = fmaxf(sd1, 0.f) + __logf(1.f + __expf(-fabsf(sd1)));
  float in_d  = (bin == 0) ? 1.f : 0.001f + spd;
  float in_d1 = (bin == 7) ? 1.f : 0.001f + spd1;

  float rw = __builtin_amdgcn_rcpf(in_w);
  float dlt = in_h * rw;
  float th = (xc - in_cw) * rw;
  float om = 1.f - th;
  float t1 = th * om;
  float num = in_h * (dlt * th * th + in_d * t1);
  float den = dlt + (in_d + in_d1 - 2.f * dlt) * t1;
  float rden = __builtin_amdgcn_rcpf(den);
  float yo = in_ch + num * rden;
  float dn = dlt * dlt * (in_d1 * th * th + 2.f * dlt * t1 + in_d * om * om);
  float ldv = __logf(dn * rden * rden);
  bool inside = (xv >= -3.f) && (xv <= 3.f);
  yout = inside ? yo : xv;
  ldout = inside ? ldv : 0.f;
}

// ---------------------------------------------------------------------------
// middle MLP layer (R13 form): in-place on the wave's 16-row strip of hH.
// ---------------------------------------------------------------------------
__device__ __forceinline__ void mid_layer_ip(f16_t* hH,
                                             const f16_t* __restrict__ wseg,
                                             const float* __restrict__ bg,
                                             int wv, int l16, int lhi, int lane) {
  f16x8 a[4];
#pragma unroll
  for (int s = 0; s < 4; ++s)
    a[s] = *(const f16x8*)&hH[(wv * 16 + l16) * 136 + s * 32 + lhi * 8];
#pragma unroll
  for (int n = 0; n < 8; ++n) {
    f32x4 acc = {0.f, 0.f, 0.f, 0.f};
#pragma unroll
    for (int s = 0; s < 4; ++s) {
      f16x8 b = *(const f16x8*)(wseg + (size_t)((n * 4 + s) * 64 + lane) * 8);
      acc = __builtin_amdgcn_mfma_f32_16x16x32_f16(a[s], b, acc, 0, 0, 0);
    }
    float bias = bg[n * 16 + l16];
#pragma unroll
    for (int r = 0; r < 4; ++r)
      hH[(wv * 16 + lhi * 4 + r) * 136 + n * 16 + l16] =
          (f16_t)elu(acc[r] + bias);
  }
}

// ---------------------------------------------------------------------------
// Kernel B: EXACT R13 structure (the 99.8 us configuration) — 64 rows/block,
// 4 waves, block-wide __syncthreads at every phase boundary, single prm
// buffer, direct scalar y2 stores. Only the spline body is leaner.
// LDS: 17408 (hH) + 12288 (prm) + 8448 (x2s) = 38144 B -> 4 blocks/CU.
// ---------------------------------------------------------------------------
__global__ __launch_bounds__(256, 4) void nsf_fused_kernel(
    const float* __restrict__ x,
    const float* __restrict__ b1g, const float* __restrict__ b2g,
    const float* __restrict__ b3g, const float* __restrict__ b4s,
    const f16_t* __restrict__ wf,
    float* __restrict__ out) {
  __shared__ f16_t hH[MTILE * 136];       // hidden state, in-place across layers
  __shared__ f16_t prm[MTILE * 4 * 24];   // spline params chunk, f16 24-slots
  __shared__ float x2s[MTILE * 33];       // x2 tile, fp32

  const int tid = threadIdx.x;
  const int lane = tid & 63;
  const int wv = tid >> 6;
  const int l16 = lane & 15, lhi = lane >> 4;
  const int row0 = blockIdx.x * MTILE;

  // ---- stage x: x1 -> out + hH (f16), x2 -> x2s (f32) ----
  {
    const float4* x4 = (const float4*)(x + (size_t)row0 * 64);
    float4* o4 = (float4*)(out + (size_t)row0 * 64);
#pragma unroll
    for (int it = 0; it < 4; ++it) {
      int idx = tid + it * 256;          // 0..1023 = 64 rows x 16 float4
      int row = idx >> 4, q = idx & 15;
      float4 v = x4[row * 16 + q];
      if (q < 8) {                       // x1 cols 0..31
        o4[row * 16 + q] = v;
        f16x4 p = {(f16_t)v.x, (f16_t)v.y, (f16_t)v.z, (f16_t)v.w};
        *(f16x4*)&hH[row * 136 + q * 4] = p;
      } else {                           // x2 cols 32..63
        int cb = row * 33 + (q - 8) * 4;
        x2s[cb + 0] = v.x; x2s[cb + 1] = v.y;
        x2s[cb + 2] = v.z; x2s[cb + 3] = v.w;
      }
    }
  }
  __syncthreads();

  // ---- layer 1: (64x32)@(32x128), K=32, in-place ----
  {
    f16x8 a = *(const f16x8*)&hH[(wv * 16 + l16) * 136 + lhi * 8];
#pragma unroll
    for (int n = 0; n < 8; ++n) {
      f16x8 b = *(const f16x8*)(wf + W1F + (size_t)(n * 64 + lane) * 8);
      f32x4 acc = {0.f, 0.f, 0.f, 0.f};
      acc = __builtin_amdgcn_mfma_f32_16x16x32_f16(a, b, acc, 0, 0, 0);
      float bias = b1g[n * 16 + l16];
#pragma unroll
      for (int r = 0; r < 4; ++r)
        hH[(wv * 16 + lhi * 4 + r) * 136 + n * 16 + l16] =
            (f16_t)elu(acc[r] + bias);
    }
  }
  __syncthreads();

  mid_layer_ip(hH, wf + W2F, b2g, wv, l16, lhi, lane);   // layer 2
  __syncthreads();
  mid_layer_ip(hH, wf + W3F, b3g, wv, l16, lhi, lane);   // layer 3
  __syncthreads();

  // ---- layer 4 + spline, 8 chunks of 4 spline-dims each ----
  {
    f16x8 a4[4];
#pragma unroll
    for (int s = 0; s < 4; ++s)
      a4[s] = *(const f16x8*)&hH[(wv * 16 + l16) * 136 + s * 32 + lhi * 8];

    const int srow = tid >> 2;   // spline row 0..63
    const int sjj = tid & 3;     // chunk-local spline dim
    float ldp = 0.f;

    for (int c = 0; c < 8; ++c) {
      // GEMM4 chunk: 92 real cols (4 dims x 23) padded to 96 (6 tiles)
#pragma unroll
      for (int n = 0; n < 6; ++n) {
        f32x4 acc = {0.f, 0.f, 0.f, 0.f};
#pragma unroll
        for (int s = 0; s < 4; ++s) {
          f16x8 b = *(const f16x8*)(wf + W4F +
                      (size_t)(((c * 6 + n) * 4 + s) * 64 + lane) * 8);
          acc = __builtin_amdgcn_mfma_f32_16x16x32_f16(a4[s], b, acc, 0, 0, 0);
        }
        int colc = n * 16 + l16;
        if (colc < 92) {
          int dm = (colc * 90) >> 11;          // colc / 23 for colc < 92
          int j = colc - dm * 23;
          float bias = b4s[c * 92 + colc];
#pragma unroll
          for (int r = 0; r < 4; ++r)
            prm[((wv * 16 + lhi * 4 + r) * 4 + dm) * 24 + j] =
                (f16_t)(acc[r] + bias);
        }
      }
      __syncthreads();

      // ---- spline: one (row, dim) task per thread ----
      {
        int jg = c * 4 + sjj;
        float xv = x2s[srow * 33 + jg];
        float y0, l0;
        rqs_task(prm + (srow * 4 + sjj) * 24, xv, y0, l0);
        out[(size_t)(row0 + srow) * 64 + 32 + jg] = y0;
        ldp += l0;
      }
      __syncthreads();
    }

    // ---- log_det: quad reduce over sjj ----
    ldp += __shfl_xor(ldp, 1, 64);
    ldp += __shfl_xor(ldp, 2, 64);
    if ((tid & 3) == 0)
      out[(size_t)BATCH * 64 + row0 + srow] = ldp;
  }
}

// ---------------------------------------------------------------------------
extern "C" void kernel_launch(void* const* d_in, const int* in_sizes, int n_in,
                              void* d_out, int out_size, void* d_ws, size_t ws_size,
                              hipStream_t stream) {
  const float* x  = (const float*)d_in[0];
  const float* W1 = (const float*)d_in[1];
  const float* b1 = (const float*)d_in[2];
  const float* W2 = (const float*)d_in[3];
  const float* b2 = (const float*)d_in[4];
  const float* W3 = (const float*)d_in[5];
  const float* b3 = (const float*)d_in[6];
  const float* W4 = (const float*)d_in[7];
  const float* b4 = (const float*)d_in[8];
  f16_t* wf = (f16_t*)d_ws;
  float* b4s = (float*)d_ws + B4S_OFF;
  float* out = (float*)d_out;

  hipLaunchKernelGGL(convert_weights_kernel, dim3(69), dim3(256), 0, stream,
                     W1, W2, W3, W4, b4, wf, b4s);
  hipLaunchKernelGGL(nsf_fused_kernel, dim3(NBLK), dim3(256), 0, stream,
                     x, b1, b2, b3, b4s, wf, out);
}

// Round 20
// 97.658 us; speedup vs baseline: 1.2505x; 1.0035x over previous
//
#include <hip/hip_runtime.h>
#include <hip/hip_bf16.h>
#include <math.h>

typedef _Float16 f16_t;
typedef _Float16 f16x4 __attribute__((ext_vector_type(4)));
typedef _Float16 f16x8 __attribute__((ext_vector_type(8)));
typedef float f32x4 __attribute__((ext_vector_type(4)));

#define BATCH 131072
#define MTILE 64               // rows per block (4 waves, 16 rows/wave)
#define NBLK (BATCH / MTILE)
#define LOG2E 1.4426950408889634f

// fragment-layout weight offsets in d_ws (elements, f16)
#define W1F 0
#define W2F 4096
#define W3F 20480
#define W4F 36864
#define B4S_OFF 67584          // float index into d_ws, 736 floats

// ---------------------------------------------------------------------------
// Kernel A: fp32 weights -> fp16 MFMA B-fragment layout.
//   col = tile*16 + (lane&15), k = kstep*32 + (lane>>4)*8 + j
// W4 laid out as 8 chunks x 92 cols padded to 96 (6 tiles).
// W4's softmax cols (col%23 < 16) pre-scaled by log2(e); b4 -> b4s likewise.
// ---------------------------------------------------------------------------
__global__ __launch_bounds__(256) void convert_weights_kernel(
    const float* __restrict__ W1, const float* __restrict__ W2,
    const float* __restrict__ W3, const float* __restrict__ W4,
    const float* __restrict__ b4, f16_t* __restrict__ wf,
    float* __restrict__ b4s) {
  int tid = blockIdx.x * 256 + threadIdx.x;
  if (tid >= 16896) {                    // tail: scale b4 -> b4s
    int i = tid - 16896;
    if (i < 736) {
      float s = ((i % 23) < 16) ? LOG2E : 1.f;
      b4s[i] = b4[i] * s;
    }
    return;
  }
  int lane = tid & 63;
  int l16 = lane & 15, lhi = lane >> 4;
  const float* W; int ncols, col, k0; bool zero = false; float scale = 1.f;
  if (tid < 512) {
    int n = tid >> 6;
    W = W1; ncols = 128; col = n * 16 + l16; k0 = lhi * 8;
  } else if (tid < 2560) {
    int g = tid - 512; int n = g >> 8, s = (g >> 6) & 3;
    W = W2; ncols = 128; col = n * 16 + l16; k0 = s * 32 + lhi * 8;
  } else if (tid < 4608) {
    int g = tid - 2560; int n = g >> 8, s = (g >> 6) & 3;
    W = W3; ncols = 128; col = n * 16 + l16; k0 = s * 32 + lhi * 8;
  } else {
    int g = tid - 4608; int t = g >> 8, s = (g >> 6) & 3;
    int c = t / 6, n = t - c * 6;
    int colc = n * 16 + l16;
    W = W4; ncols = 736; col = c * 92 + colc; k0 = s * 32 + lhi * 8;
    zero = (colc >= 92);
    if (!zero) scale = ((col % 23) < 16) ? LOG2E : 1.f;
  }
  f16x8 v;
#pragma unroll
  for (int j = 0; j < 8; ++j)
    v[j] = zero ? (f16_t)0.f : (f16_t)(W[(k0 + j) * ncols + col] * scale);
  *(f16x8*)(wf + (size_t)tid * 8) = v;
}

__device__ __forceinline__ float elu(float v) {
  return v > 0.f ? v : (__expf(v) - 1.f);
}

// ---------------------------------------------------------------------------
// spline for one (row, dim) task; P = 24-f16 param slot (16B-aligned).
// R18-validated lean form: exp2-domain softmax, deferred softplus,
// select-then-fma widths/heights, rcp divides, fused log.
// ---------------------------------------------------------------------------
__device__ __forceinline__ void rqs_task(const f16_t* P, float xv,
                                         float& yout, float& ldout) {
  f16x8 pw = *(const f16x8*)P;
  f16x8 ph = *(const f16x8*)(P + 8);
  f16x8 pd = *(const f16x8*)(P + 16);   // [7] is pad, unused

  float ew[8], sw = 0.f;
#pragma unroll
  for (int i = 0; i < 8; ++i) { ew[i] = exp2f((float)pw[i]); sw += ew[i]; }
  float invw = 0.992f * __builtin_amdgcn_rcpf(sw);
  float cw[8]; cw[0] = -3.f;
  float accw = 0.f;
#pragma unroll
  for (int i = 0; i < 7; ++i) {
    accw += 0.001f + ew[i] * invw;
    cw[i + 1] = -3.f + 6.f * accw;
  }

  float eh[8], sh = 0.f;
#pragma unroll
  for (int i = 0; i < 8; ++i) { eh[i] = exp2f((float)ph[i]); sh += eh[i]; }
  float invh = 0.992f * __builtin_amdgcn_rcpf(sh);
  float ch[8]; ch[0] = -3.f;
  float acch = 0.f;
#pragma unroll
  for (int i = 0; i < 7; ++i) {
    acch += 0.001f + eh[i] * invh;
    ch[i + 1] = -3.f + 6.f * acch;
  }

  float xc = fminf(fmaxf(xv, -3.f), 3.f);
  int bin = 0;
#pragma unroll
  for (int i = 1; i < 8; ++i) bin += (xc >= cw[i]) ? 1 : 0;

  float in_cw = cw[0], in_ch = ch[0];
  float ewsel = ew[0], ehsel = eh[0];
  float sd  = (float)pd[0];
  float sd1 = (float)pd[0];
#pragma unroll
  for (int i = 1; i < 8; ++i) {
    bool g = (bin >= i);
    in_cw = g ? cw[i] : in_cw;  in_ch = g ? ch[i] : in_ch;
    ewsel = g ? ew[i] : ewsel;  ehsel = g ? eh[i] : ehsel;
    sd    = g ? (float)pd[i - 1] : sd;
  }
#pragma unroll
  for (int i = 1; i < 7; ++i)
    sd1 = (bin >= i) ? (float)pd[i] : sd1;

  float in_w = fmaf(ewsel * invw, 6.f, 0.006f);
  float in_h = fmaf(ehsel * invh, 6.f, 0.006f);

  float spd  = fmaxf(sd,  0.f) + __logf(1.f + __expf(-fabsf(sd)));
  float spd1 = fmaxf(sd1, 0.f) + __logf(1.f + __expf(-fabsf(sd1)));
  float in_d  = (bin == 0) ? 1.f : 0.001f + spd;
  float in_d1 = (bin == 7) ? 1.f : 0.001f + spd1;

  float rw = __builtin_amdgcn_rcpf(in_w);
  float dlt = in_h * rw;
  float th = (xc - in_cw) * rw;
  float om = 1.f - th;
  float t1 = th * om;
  float num = in_h * (dlt * th * th + in_d * t1);
  float den = dlt + (in_d + in_d1 - 2.f * dlt) * t1;
  float rden = __builtin_amdgcn_rcpf(den);
  float yo = in_ch + num * rden;
  float dn = dlt * dlt * (in_d1 * th * th + 2.f * dlt * t1 + in_d * om * om);
  float ldv = __logf(dn * rden * rden);
  bool inside = (xv >= -3.f) && (xv <= 3.f);
  yout = inside ? yo : xv;
  ldout = inside ? ldv : 0.f;
}

// ---------------------------------------------------------------------------
// middle MLP layer (R13 form): in-place on the wave's 16-row strip of hH.
// ---------------------------------------------------------------------------
__device__ __forceinline__ void mid_layer_ip(f16_t* hH,
                                             const f16_t* __restrict__ wseg,
                                             const float* __restrict__ bg,
                                             int wv, int l16, int lhi, int lane) {
  f16x8 a[4];
#pragma unroll
  for (int s = 0; s < 4; ++s)
    a[s] = *(const f16x8*)&hH[(wv * 16 + l16) * 136 + s * 32 + lhi * 8];
#pragma unroll
  for (int n = 0; n < 8; ++n) {
    f32x4 acc = {0.f, 0.f, 0.f, 0.f};
#pragma unroll
    for (int s = 0; s < 4; ++s) {
      f16x8 b = *(const f16x8*)(wseg + (size_t)((n * 4 + s) * 64 + lane) * 8);
      acc = __builtin_amdgcn_mfma_f32_16x16x32_f16(a[s], b, acc, 0, 0, 0);
    }
    float bias = bg[n * 16 + l16];
#pragma unroll
    for (int r = 0; r < 4; ++r)
      hH[(wv * 16 + lhi * 4 + r) * 136 + n * 16 + l16] =
          (f16_t)elu(acc[r] + bias);
  }
}

// ---------------------------------------------------------------------------
// Kernel B: R18 structure with chunk-loop barriers relaxed to wave_barrier.
// Hazard audit: GEMM4 of wave w writes prm slots [64w,64w+64) only (slot =
// (wv*16+lhi*4+r)*4+dm); spline reader of slot s is thread tid==s (same
// wave). x2s read-only after stage; a4 in registers. So the chunk loop
// needs only wave-level ordering -> the 4 waves free-run and interleave
// spline VALU with GEMM L2 loads on each SIMD. Stage/layer barriers stay.
// LDS: 17408 (hH) + 12288 (prm) + 8448 (x2s) = 38144 B -> 4 blocks/CU.
// ---------------------------------------------------------------------------
__global__ __launch_bounds__(256, 4) void nsf_fused_kernel(
    const float* __restrict__ x,
    const float* __restrict__ b1g, const float* __restrict__ b2g,
    const float* __restrict__ b3g, const float* __restrict__ b4s,
    const f16_t* __restrict__ wf,
    float* __restrict__ out) {
  __shared__ f16_t hH[MTILE * 136];       // hidden state, in-place across layers
  __shared__ f16_t prm[MTILE * 4 * 24];   // spline params chunk, f16 24-slots
  __shared__ float x2s[MTILE * 33];       // x2 tile, fp32

  const int tid = threadIdx.x;
  const int lane = tid & 63;
  const int wv = tid >> 6;
  const int l16 = lane & 15, lhi = lane >> 4;
  const int row0 = blockIdx.x * MTILE;

  // ---- stage x: x1 -> out + hH (f16), x2 -> x2s (f32) ----
  {
    const float4* x4 = (const float4*)(x + (size_t)row0 * 64);
    float4* o4 = (float4*)(out + (size_t)row0 * 64);
#pragma unroll
    for (int it = 0; it < 4; ++it) {
      int idx = tid + it * 256;          // 0..1023 = 64 rows x 16 float4
      int row = idx >> 4, q = idx & 15;
      float4 v = x4[row * 16 + q];
      if (q < 8) {                       // x1 cols 0..31
        o4[row * 16 + q] = v;
        f16x4 p = {(f16_t)v.x, (f16_t)v.y, (f16_t)v.z, (f16_t)v.w};
        *(f16x4*)&hH[row * 136 + q * 4] = p;
      } else {                           // x2 cols 32..63
        int cb = row * 33 + (q - 8) * 4;
        x2s[cb + 0] = v.x; x2s[cb + 1] = v.y;
        x2s[cb + 2] = v.z; x2s[cb + 3] = v.w;
      }
    }
  }
  __syncthreads();

  // ---- layer 1: (64x32)@(32x128), K=32, in-place ----
  {
    f16x8 a = *(const f16x8*)&hH[(wv * 16 + l16) * 136 + lhi * 8];
#pragma unroll
    for (int n = 0; n < 8; ++n) {
      f16x8 b = *(const f16x8*)(wf + W1F + (size_t)(n * 64 + lane) * 8);
      f32x4 acc = {0.f, 0.f, 0.f, 0.f};
      acc = __builtin_amdgcn_mfma_f32_16x16x32_f16(a, b, acc, 0, 0, 0);
      float bias = b1g[n * 16 + l16];
#pragma unroll
      for (int r = 0; r < 4; ++r)
        hH[(wv * 16 + lhi * 4 + r) * 136 + n * 16 + l16] =
            (f16_t)elu(acc[r] + bias);
    }
  }
  __syncthreads();

  mid_layer_ip(hH, wf + W2F, b2g, wv, l16, lhi, lane);   // layer 2
  __syncthreads();
  mid_layer_ip(hH, wf + W3F, b3g, wv, l16, lhi, lane);   // layer 3
  __syncthreads();

  // ---- layer 4 + spline, 8 chunks; wave-level sync only ----
  {
    f16x8 a4[4];
#pragma unroll
    for (int s = 0; s < 4; ++s)
      a4[s] = *(const f16x8*)&hH[(wv * 16 + l16) * 136 + s * 32 + lhi * 8];

    const int srow = tid >> 2;   // spline row 0..63 (== wave's own rows)
    const int sjj = tid & 3;     // chunk-local spline dim
    float ldp = 0.f;

    for (int c = 0; c < 8; ++c) {
      // GEMM4 chunk: 92 real cols (4 dims x 23) padded to 96 (6 tiles)
#pragma unroll
      for (int n = 0; n < 6; ++n) {
        f32x4 acc = {0.f, 0.f, 0.f, 0.f};
#pragma unroll
        for (int s = 0; s < 4; ++s) {
          f16x8 b = *(const f16x8*)(wf + W4F +
                      (size_t)(((c * 6 + n) * 4 + s) * 64 + lane) * 8);
          acc = __builtin_amdgcn_mfma_f32_16x16x32_f16(a4[s], b, acc, 0, 0, 0);
        }
        int colc = n * 16 + l16;
        if (colc < 92) {
          int dm = (colc * 90) >> 11;          // colc / 23 for colc < 92
          int j = colc - dm * 23;
          float bias = b4s[c * 92 + colc];
#pragma unroll
          for (int r = 0; r < 4; ++r)
            prm[((wv * 16 + lhi * 4 + r) * 4 + dm) * 24 + j] =
                (f16_t)(acc[r] + bias);
        }
      }
      __builtin_amdgcn_wave_barrier();     // writer==reader wave; order only

      // ---- spline: one (row, dim) task per thread (slot == tid) ----
      {
        int jg = c * 4 + sjj;
        float xv = x2s[srow * 33 + jg];
        float y0, l0;
        rqs_task(prm + tid * 24, xv, y0, l0);
        out[(size_t)(row0 + srow) * 64 + 32 + jg] = y0;
        ldp += l0;
      }
      __builtin_amdgcn_wave_barrier();     // WAR before next chunk's writes
    }

    // ---- log_det: quad reduce over sjj ----
    ldp += __shfl_xor(ldp, 1, 64);
    ldp += __shfl_xor(ldp, 2, 64);
    if ((tid & 3) == 0)
      out[(size_t)BATCH * 64 + row0 + srow] = ldp;
  }
}

// ---------------------------------------------------------------------------
extern "C" void kernel_launch(void* const* d_in, const int* in_sizes, int n_in,
                              void* d_out, int out_size, void* d_ws, size_t ws_size,
                              hipStream_t stream) {
  const float* x  = (const float*)d_in[0];
  const float* W1 = (const float*)d_in[1];
  const float* b1 = (const float*)d_in[2];
  const float* W2 = (const float*)d_in[3];
  const float* b2 = (const float*)d_in[4];
  const float* W3 = (const float*)d_in[5];
  const float* b3 = (const float*)d_in[6];
  const float* W4 = (const float*)d_in[7];
  const float* b4 = (const float*)d_in[8];
  f16_t* wf = (f16_t*)d_ws;
  float* b4s = (float*)d_ws + B4S_OFF;
  float* out = (float*)d_out;

  hipLaunchKernelGGL(convert_weights_kernel, dim3(69), dim3(256), 0, stream,
                     W1, W2, W3, W4, b4, wf, b4s);
  hipLaunchKernelGGL(nsf_fused_kernel, dim3(NBLK), dim3(256), 0, stream,
                     x, b1, b2, b3, b4s, wf, out);
}